// Round 5
// baseline (159.966 us; speedup 1.0000x reference)
//
#include <hip/hip_runtime.h>
#include <math.h>

namespace {
constexpr int IN_FEATS = 768;
constexpr int HIDDEN   = 128;
constexpr int G        = 1024;
constexpr int NPG      = 256;          // nodes per graph
constexpr int C4       = IN_FEATS / 4; // 192 float4 columns per row
constexpr int NT       = 384;          // 6 waves
constexpr int GPB      = 2;            // graphs per block
constexpr int NB       = G / GPB;      // 512 blocks
typedef float f32x4 __attribute__((ext_vector_type(4)));  // nontemporal-compatible
}

// One block per 2 graphs. Exact closed form of the reference (verified R0/R1):
//   deg(orig)=2, deg(prompt)=259, deg(class)=2; ainv = 1/sqrt(518)
//   r_g   = relu(ainv*(S_g@W1) + ainv*(h0+h1) + hp/259 + b1)
//   rc_k  = relu(ainv*hp + 0.5*h_k + b1)
//   v_gk  = ainv*(r_g@W2) + 0.5*(rc_k@W2) + b2
//   out   = log_softmax(v_gk @ Wfc + bfc)
// where S_g = column-sum of graph g's 256 rows, hp = prompt@W1, h_k = class_k@W1.
// hp/h0/h1 ride on phase B's W1 loads (load-bound, so ~free).
__global__ __launch_bounds__(NT) void fused_kernel(
    const float* __restrict__ x, const float* __restrict__ prompt,
    const float* __restrict__ cls,
    const float* __restrict__ W1, const float* __restrict__ b1,
    const float* __restrict__ W2, const float* __restrict__ b2,
    const float* __restrict__ Wfc, const float* __restrict__ bfc,
    float* __restrict__ out)
{
    __shared__ __align__(16) float S[GPB][IN_FEATS];   // 6 KB graph column-sums
    __shared__ f32x4  partA[GPB][2][C4];               // 12 KB phase-A parity partials
    __shared__ float  pb[3][5][HIDDEN];                // 7.5 KB phase-B seg partials
    __shared__ __align__(16) float rbuf[4][HIDDEN];    // 2 KB r0,r1,rc0,rc1
    __shared__ float  red[2][2];

    const int g0  = blockIdx.x * GPB;
    const int tid = threadIdx.x;
    const float ainv = 1.0f / sqrtf(518.0f);

    // ---- Phase A: both graphs' column sums, interleaved (8 loads in flight)
    const int p  = tid / C4;   // row parity 0/1
    const int c4 = tid % C4;   // float4 column
    const f32x4* xb  = reinterpret_cast<const f32x4*>(x);
    const f32x4* xp0 = xb + ((size_t)(g0 + 0) * NPG + p) * C4 + c4;
    const f32x4* xp1 = xb + ((size_t)(g0 + 1) * NPG + p) * C4 + c4;
    {
        f32x4 a0 = (f32x4)0.0f, a1 = a0, a2 = a0, a3 = a0;   // g0
        f32x4 b0 = a0, b1 = a0, b2 = a0, b3 = a0;            // g1
        for (int i = 0; i < NPG / 2; i += 4) {
            const f32x4 v0 = __builtin_nontemporal_load(xp0 + (size_t)(2 * (i + 0)) * C4);
            const f32x4 v1 = __builtin_nontemporal_load(xp0 + (size_t)(2 * (i + 1)) * C4);
            const f32x4 v2 = __builtin_nontemporal_load(xp0 + (size_t)(2 * (i + 2)) * C4);
            const f32x4 v3 = __builtin_nontemporal_load(xp0 + (size_t)(2 * (i + 3)) * C4);
            const f32x4 w0 = __builtin_nontemporal_load(xp1 + (size_t)(2 * (i + 0)) * C4);
            const f32x4 w1 = __builtin_nontemporal_load(xp1 + (size_t)(2 * (i + 1)) * C4);
            const f32x4 w2 = __builtin_nontemporal_load(xp1 + (size_t)(2 * (i + 2)) * C4);
            const f32x4 w3 = __builtin_nontemporal_load(xp1 + (size_t)(2 * (i + 3)) * C4);
            a0 += v0; a1 += v1; a2 += v2; a3 += v3;
            b0 += w0; b1 += w1; b2 += w2; b3 += w3;
        }
        partA[0][p][c4] = (a0 + a1) + (a2 + a3);
        partA[1][p][c4] = (b0 + b1) + (b2 + b3);
    }
    __syncthreads();
    {
        const int gg = tid / C4;   // all 384 threads active: 2 graphs x 192 cols
        const int c  = tid % C4;
        const f32x4 q0 = partA[gg][0][c], q1 = partA[gg][1][c];
        *reinterpret_cast<f32x4*>(&S[gg][c * 4]) = q0 + q1;
    }
    __syncthreads();

    // ---- Phase B: five 768->128 matvecs sharing each W1 load -------------
    {
        const int seg = tid >> 7;          // 0..2, c-range of 256
        const int j   = tid & (HIDDEN - 1);
        const int cb  = seg * 256;
        const float* w1p = W1 + (size_t)cb * HIDDEN + j;
        float t0 = 0.f, t1 = 0.f, hp = 0.f, h0 = 0.f, h1 = 0.f;
        for (int cc = 0; cc < 256; cc += 4) {
            const int c = cb + cc;
            const f32x4 s0 = *reinterpret_cast<const f32x4*>(&S[0][c]); // ds_read_b128
            const f32x4 s1 = *reinterpret_cast<const f32x4*>(&S[1][c]);
            const f32x4 pv = *reinterpret_cast<const f32x4*>(prompt + c);      // uniform
            const f32x4 k0 = *reinterpret_cast<const f32x4*>(cls + c);         // uniform
            const f32x4 k1 = *reinterpret_cast<const f32x4*>(cls + IN_FEATS + c);
            const float w0 = w1p[(size_t)(cc + 0) * HIDDEN];
            const float w1 = w1p[(size_t)(cc + 1) * HIDDEN];
            const float w2 = w1p[(size_t)(cc + 2) * HIDDEN];
            const float w3 = w1p[(size_t)(cc + 3) * HIDDEN];
            t0 = fmaf(s0.x, w0, t0); t1 = fmaf(s1.x, w0, t1);
            hp = fmaf(pv.x, w0, hp); h0 = fmaf(k0.x, w0, h0); h1 = fmaf(k1.x, w0, h1);
            t0 = fmaf(s0.y, w1, t0); t1 = fmaf(s1.y, w1, t1);
            hp = fmaf(pv.y, w1, hp); h0 = fmaf(k0.y, w1, h0); h1 = fmaf(k1.y, w1, h1);
            t0 = fmaf(s0.z, w2, t0); t1 = fmaf(s1.z, w2, t1);
            hp = fmaf(pv.z, w2, hp); h0 = fmaf(k0.z, w2, h0); h1 = fmaf(k1.z, w2, h1);
            t0 = fmaf(s0.w, w3, t0); t1 = fmaf(s1.w, w3, t1);
            hp = fmaf(pv.w, w3, hp); h0 = fmaf(k0.w, w3, h0); h1 = fmaf(k1.w, w3, h1);
        }
        pb[seg][0][j] = t0; pb[seg][1][j] = t1;
        pb[seg][2][j] = hp; pb[seg][3][j] = h0; pb[seg][4][j] = h1;
    }
    __syncthreads();
    if (tid < HIDDEN) {
        const float t0 = pb[0][0][tid] + pb[1][0][tid] + pb[2][0][tid];
        const float t1 = pb[0][1][tid] + pb[1][1][tid] + pb[2][1][tid];
        const float hp = pb[0][2][tid] + pb[1][2][tid] + pb[2][2][tid];
        const float h0 = pb[0][3][tid] + pb[1][3][tid] + pb[2][3][tid];
        const float h1 = pb[0][4][tid] + pb[1][4][tid] + pb[2][4][tid];
        const float b  = b1[tid];
        const float C1 = ainv * (h0 + h1) + hp * (1.0f / 259.0f) + b;
        rbuf[0][tid] = fmaxf(fmaf(ainv, t0, C1), 0.f);                  // r_g0
        rbuf[1][tid] = fmaxf(fmaf(ainv, t1, C1), 0.f);                  // r_g1
        rbuf[2][tid] = fmaxf(fmaf(ainv, hp, fmaf(0.5f, h0, b)), 0.f);   // rc0
        rbuf[3][tid] = fmaxf(fmaf(ainv, hp, fmaf(0.5f, h1, b)), 0.f);   // rc1
    }
    __syncthreads();

    // ---- Phase C: four 128->128 matvecs sharing each W2 load -------------
    float u0 = 0.f, u1 = 0.f, uc0 = 0.f, uc1 = 0.f;
    if (tid < HIDDEN) {
        const float* w2p = W2 + tid;
        for (int c = 0; c < HIDDEN; c += 4) {
            const f32x4 r0 = *reinterpret_cast<const f32x4*>(&rbuf[0][c]);
            const f32x4 r1 = *reinterpret_cast<const f32x4*>(&rbuf[1][c]);
            const f32x4 q0 = *reinterpret_cast<const f32x4*>(&rbuf[2][c]);
            const f32x4 q1 = *reinterpret_cast<const f32x4*>(&rbuf[3][c]);
            const float wa = w2p[(size_t)(c + 0) * HIDDEN];
            const float wb = w2p[(size_t)(c + 1) * HIDDEN];
            const float wc = w2p[(size_t)(c + 2) * HIDDEN];
            const float wd = w2p[(size_t)(c + 3) * HIDDEN];
            u0  = fmaf(r0.x, wa, u0);  u1  = fmaf(r1.x, wa, u1);
            uc0 = fmaf(q0.x, wa, uc0); uc1 = fmaf(q1.x, wa, uc1);
            u0  = fmaf(r0.y, wb, u0);  u1  = fmaf(r1.y, wb, u1);
            uc0 = fmaf(q0.y, wb, uc0); uc1 = fmaf(q1.y, wb, uc1);
            u0  = fmaf(r0.z, wc, u0);  u1  = fmaf(r1.z, wc, u1);
            uc0 = fmaf(q0.z, wc, uc0); uc1 = fmaf(q1.z, wc, uc1);
            u0  = fmaf(r0.w, wd, u0);  u1  = fmaf(r1.w, wd, u1);
            uc0 = fmaf(q0.w, wd, uc0); uc1 = fmaf(q1.w, wd, uc1);
        }
    }

    // ---- Phase D: logits + log_softmax per (graph, class) ----------------
    const float bfc0 = bfc[0], bfc1 = bfc[1];
    for (int gg = 0; gg < GPB; ++gg) {
        for (int k = 0; k < 2; ++k) {
            float p0 = 0.f, p1 = 0.f;
            if (tid < HIDDEN) {
                const float ug = (gg == 0) ? u0 : u1;
                const float uk = (k == 0) ? uc0 : uc1;
                const float v  = fmaf(ainv, ug, fmaf(0.5f, uk, b2[tid]));
                p0 = v * Wfc[tid * 2 + 0];
                p1 = v * Wfc[tid * 2 + 1];
                #pragma unroll
                for (int off = 32; off > 0; off >>= 1) {
                    p0 += __shfl_down(p0, off);
                    p1 += __shfl_down(p1, off);
                }
                if ((tid & 63) == 0) { red[tid >> 6][0] = p0; red[tid >> 6][1] = p1; }
            }
            __syncthreads();
            if (tid == 0) {
                const float l0 = red[0][0] + red[1][0] + bfc0;
                const float l1 = red[0][1] + red[1][1] + bfc1;
                const float m   = fmaxf(l0, l1);
                const float lse = m + logf(expf(l0 - m) + expf(l1 - m));
                float* o = out + ((size_t)(g0 + gg) * 2 + k) * 2;
                o[0] = l0 - lse;
                o[1] = l1 - lse;
            }
            __syncthreads();
        }
    }
}

extern "C" void kernel_launch(void* const* d_in, const int* in_sizes, int n_in,
                              void* d_out, int out_size, void* d_ws, size_t ws_size,
                              hipStream_t stream) {
    const float* x      = (const float*)d_in[0];
    const float* prompt = (const float*)d_in[1];
    const float* cls    = (const float*)d_in[2];
    const float* W1     = (const float*)d_in[3];
    const float* b1     = (const float*)d_in[4];
    const float* W2     = (const float*)d_in[5];
    const float* b2     = (const float*)d_in[6];
    const float* Wfc    = (const float*)d_in[7];
    const float* bfc    = (const float*)d_in[8];
    float* out = (float*)d_out;

    fused_kernel<<<NB, NT, 0, stream>>>(x, prompt, cls, W1, b1, W2, b2,
                                        Wfc, bfc, out);
}

// Round 6
// 154.138 us; speedup vs baseline: 1.0378x; 1.0378x over previous
//
#include <hip/hip_runtime.h>
#include <math.h>

namespace {
constexpr int IN_FEATS = 768;
constexpr int HIDDEN   = 128;
constexpr int G        = 1024;
constexpr int NPG      = 256;          // nodes per graph
constexpr int C4       = IN_FEATS / 4; // 192 float4 columns per row
constexpr int NT       = 384;          // 6 waves
constexpr int GPB      = 2;            // graphs per block
constexpr int NB       = G / GPB;      // 512 blocks
typedef float f32x4 __attribute__((ext_vector_type(4)));
}

// One block per 2 graphs, software-pipelined:
//   A0: stream g0's rows -> S[0]
//   B0: t0/hp/h0/h1 matvecs over W1  ||  g1's x-stream interleaved (2 loads/iter)
//   B1: t1 matvec over W1 (short, L2-bound) -> only exposed tail
//   C:  4 matvecs over W2;  D: logits + log_softmax
// Closed form (verified R0-R4): deg(orig)=2, deg(prompt)=259, deg(class)=2;
//   ainv = 1/sqrt(518); r_g = relu(ainv*t_g + ainv*(h0+h1) + hp/259 + b1)
//   rc_k = relu(ainv*hp + 0.5*h_k + b1); v_gk = ainv*(r_g@W2) + 0.5*(rc_k@W2) + b2
__global__ __launch_bounds__(NT) void fused_kernel(
    const float* __restrict__ x, const float* __restrict__ prompt,
    const float* __restrict__ cls,
    const float* __restrict__ W1, const float* __restrict__ b1,
    const float* __restrict__ W2, const float* __restrict__ b2,
    const float* __restrict__ Wfc, const float* __restrict__ bfc,
    float* __restrict__ out)
{
    __shared__ __align__(16) float S[GPB][IN_FEATS];   // 6 KB
    __shared__ f32x4  partA[2][C4];                    // 6 KB (reused g0 then g1)
    __shared__ float  pb[3][5][HIDDEN];                // 7.5 KB (t0,hp,h0,h1,t1)
    __shared__ __align__(16) float rbuf[4][HIDDEN];    // 2 KB
    __shared__ float  red[2][2];

    const int g0  = blockIdx.x * GPB;
    const int tid = threadIdx.x;
    const float ainv = 1.0f / sqrtf(518.0f);

    const int p  = tid / C4;   // row parity 0/1
    const int c4 = tid % C4;   // float4 column
    const f32x4* xb  = reinterpret_cast<const f32x4*>(x);
    const f32x4* xp0 = xb + ((size_t)(g0 + 0) * NPG + p) * C4 + c4;
    const f32x4* xp1 = xb + ((size_t)(g0 + 1) * NPG + p) * C4 + c4;

    // ---- Phase A0: g0 column sum (identical structure to R4) -------------
    {
        f32x4 a0 = (f32x4)0.0f, a1 = a0, a2 = a0, a3 = a0;
        for (int i = 0; i < NPG / 2; i += 4) {
            const f32x4 v0 = __builtin_nontemporal_load(xp0 + (size_t)(2 * (i + 0)) * C4);
            const f32x4 v1 = __builtin_nontemporal_load(xp0 + (size_t)(2 * (i + 1)) * C4);
            const f32x4 v2 = __builtin_nontemporal_load(xp0 + (size_t)(2 * (i + 2)) * C4);
            const f32x4 v3 = __builtin_nontemporal_load(xp0 + (size_t)(2 * (i + 3)) * C4);
            a0 += v0; a1 += v1; a2 += v2; a3 += v3;
        }
        partA[p][c4] = (a0 + a1) + (a2 + a3);
    }
    __syncthreads();
    if (tid < C4) {
        const f32x4 q0 = partA[0][tid], q1 = partA[1][tid];
        *reinterpret_cast<f32x4*>(&S[0][tid * 4]) = q0 + q1;
    }
    __syncthreads();

    // ---- Phase B0: t0/hp/h0/h1 matvecs, g1 x-stream interleaved ----------
    {
        const int seg = tid >> 7;          // 0..2, c-range of 256
        const int j   = tid & (HIDDEN - 1);
        const int cb  = seg * 256;
        const float* w1p = W1 + (size_t)cb * HIDDEN + j;
        float t0 = 0.f, hp = 0.f, h0 = 0.f, h1 = 0.f;
        f32x4 a0 = (f32x4)0.0f, a1 = a0, a2 = a0, a3 = a0;   // g1 accumulators

#define B0_COLS(CC)                                                          \
        {                                                                    \
            const int c = cb + (CC);                                         \
            const f32x4 s0 = *reinterpret_cast<const f32x4*>(&S[0][c]);      \
            const f32x4 pv = *reinterpret_cast<const f32x4*>(prompt + c);    \
            const f32x4 k0 = *reinterpret_cast<const f32x4*>(cls + c);       \
            const f32x4 k1 = *reinterpret_cast<const f32x4*>(cls + IN_FEATS + c); \
            const float w0 = w1p[(size_t)((CC) + 0) * HIDDEN];               \
            const float w1 = w1p[(size_t)((CC) + 1) * HIDDEN];               \
            const float w2 = w1p[(size_t)((CC) + 2) * HIDDEN];               \
            const float w3 = w1p[(size_t)((CC) + 3) * HIDDEN];               \
            t0 = fmaf(s0.x, w0, t0); hp = fmaf(pv.x, w0, hp);                \
            h0 = fmaf(k0.x, w0, h0); h1 = fmaf(k1.x, w0, h1);                \
            t0 = fmaf(s0.y, w1, t0); hp = fmaf(pv.y, w1, hp);                \
            h0 = fmaf(k0.y, w1, h0); h1 = fmaf(k1.y, w1, h1);                \
            t0 = fmaf(s0.z, w2, t0); hp = fmaf(pv.z, w2, hp);                \
            h0 = fmaf(k0.z, w2, h0); h1 = fmaf(k1.z, w2, h1);                \
            t0 = fmaf(s0.w, w3, t0); hp = fmaf(pv.w, w3, hp);                \
            h0 = fmaf(k0.w, w3, h0); h1 = fmaf(k1.w, w3, h1);                \
        }

        for (int cc = 0; cc < 256; cc += 8) {
            const int l = cc >> 1;   // g1 load index pair (l, l+1), rows 2l/2l+2
            const f32x4 xv0 = __builtin_nontemporal_load(xp1 + (size_t)(2 * (l + 0)) * C4);
            const f32x4 xv1 = __builtin_nontemporal_load(xp1 + (size_t)(2 * (l + 1)) * C4);
            B0_COLS(cc);
            a0 += xv0; a1 += xv1;
            const f32x4 xv2 = __builtin_nontemporal_load(xp1 + (size_t)(2 * (l + 2)) * C4);
            const f32x4 xv3 = __builtin_nontemporal_load(xp1 + (size_t)(2 * (l + 3)) * C4);
            B0_COLS(cc + 4);
            a2 += xv2; a3 += xv3;
        }
#undef B0_COLS
        pb[seg][0][j] = t0; pb[seg][1][j] = hp;
        pb[seg][2][j] = h0; pb[seg][3][j] = h1;
        partA[p][c4] = (a0 + a1) + (a2 + a3);   // safe: partA last read before B0 barrier
    }
    __syncthreads();
    if (tid < C4) {
        const f32x4 q0 = partA[0][tid], q1 = partA[1][tid];
        *reinterpret_cast<f32x4*>(&S[1][tid * 4]) = q0 + q1;
    }
    __syncthreads();

    // ---- Phase B1: t1 matvec only (the short exposed tail) ---------------
    {
        const int seg = tid >> 7;
        const int j   = tid & (HIDDEN - 1);
        const int cb  = seg * 256;
        const float* w1p = W1 + (size_t)cb * HIDDEN + j;
        float t1 = 0.f;
        for (int cc = 0; cc < 256; cc += 4) {
            const int c = cb + cc;
            const f32x4 s1 = *reinterpret_cast<const f32x4*>(&S[1][c]);
            const float w0 = w1p[(size_t)(cc + 0) * HIDDEN];
            const float w1 = w1p[(size_t)(cc + 1) * HIDDEN];
            const float w2 = w1p[(size_t)(cc + 2) * HIDDEN];
            const float w3 = w1p[(size_t)(cc + 3) * HIDDEN];
            t1 = fmaf(s1.x, w0, t1);
            t1 = fmaf(s1.y, w1, t1);
            t1 = fmaf(s1.z, w2, t1);
            t1 = fmaf(s1.w, w3, t1);
        }
        pb[seg][4][j] = t1;
    }
    __syncthreads();
    if (tid < HIDDEN) {
        const float t0 = pb[0][0][tid] + pb[1][0][tid] + pb[2][0][tid];
        const float hp = pb[0][1][tid] + pb[1][1][tid] + pb[2][1][tid];
        const float h0 = pb[0][2][tid] + pb[1][2][tid] + pb[2][2][tid];
        const float h1 = pb[0][3][tid] + pb[1][3][tid] + pb[2][3][tid];
        const float t1 = pb[0][4][tid] + pb[1][4][tid] + pb[2][4][tid];
        const float b  = b1[tid];
        const float C1 = ainv * (h0 + h1) + hp * (1.0f / 259.0f) + b;
        rbuf[0][tid] = fmaxf(fmaf(ainv, t0, C1), 0.f);                  // r_g0
        rbuf[1][tid] = fmaxf(fmaf(ainv, t1, C1), 0.f);                  // r_g1
        rbuf[2][tid] = fmaxf(fmaf(ainv, hp, fmaf(0.5f, h0, b)), 0.f);   // rc0
        rbuf[3][tid] = fmaxf(fmaf(ainv, hp, fmaf(0.5f, h1, b)), 0.f);   // rc1
    }
    __syncthreads();

    // ---- Phase C: four 128->128 matvecs sharing each W2 load -------------
    float u0 = 0.f, u1 = 0.f, uc0 = 0.f, uc1 = 0.f;
    if (tid < HIDDEN) {
        const float* w2p = W2 + tid;
        for (int c = 0; c < HIDDEN; c += 4) {
            const f32x4 r0 = *reinterpret_cast<const f32x4*>(&rbuf[0][c]);
            const f32x4 r1 = *reinterpret_cast<const f32x4*>(&rbuf[1][c]);
            const f32x4 q0 = *reinterpret_cast<const f32x4*>(&rbuf[2][c]);
            const f32x4 q1 = *reinterpret_cast<const f32x4*>(&rbuf[3][c]);
            const float wa = w2p[(size_t)(c + 0) * HIDDEN];
            const float wb = w2p[(size_t)(c + 1) * HIDDEN];
            const float wc = w2p[(size_t)(c + 2) * HIDDEN];
            const float wd = w2p[(size_t)(c + 3) * HIDDEN];
            u0  = fmaf(r0.x, wa, u0);  u1  = fmaf(r1.x, wa, u1);
            uc0 = fmaf(q0.x, wa, uc0); uc1 = fmaf(q1.x, wa, uc1);
            u0  = fmaf(r0.y, wb, u0);  u1  = fmaf(r1.y, wb, u1);
            uc0 = fmaf(q0.y, wb, uc0); uc1 = fmaf(q1.y, wb, uc1);
            u0  = fmaf(r0.z, wc, u0);  u1  = fmaf(r1.z, wc, u1);
            uc0 = fmaf(q0.z, wc, uc0); uc1 = fmaf(q1.z, wc, uc1);
            u0  = fmaf(r0.w, wd, u0);  u1  = fmaf(r1.w, wd, u1);
            uc0 = fmaf(q0.w, wd, uc0); uc1 = fmaf(q1.w, wd, uc1);
        }
    }

    // ---- Phase D: logits + log_softmax per (graph, class) ----------------
    const float bfc0 = bfc[0], bfc1 = bfc[1];
    for (int gg = 0; gg < GPB; ++gg) {
        for (int k = 0; k < 2; ++k) {
            float p0 = 0.f, p1 = 0.f;
            if (tid < HIDDEN) {
                const float ug = (gg == 0) ? u0 : u1;
                const float uk = (k == 0) ? uc0 : uc1;
                const float v  = fmaf(ainv, ug, fmaf(0.5f, uk, b2[tid]));
                p0 = v * Wfc[tid * 2 + 0];
                p1 = v * Wfc[tid * 2 + 1];
                #pragma unroll
                for (int off = 32; off > 0; off >>= 1) {
                    p0 += __shfl_down(p0, off);
                    p1 += __shfl_down(p1, off);
                }
                if ((tid & 63) == 0) { red[tid >> 6][0] = p0; red[tid >> 6][1] = p1; }
            }
            __syncthreads();
            if (tid == 0) {
                const float l0 = red[0][0] + red[1][0] + bfc0;
                const float l1 = red[0][1] + red[1][1] + bfc1;
                const float m   = fmaxf(l0, l1);
                const float lse = m + logf(expf(l0 - m) + expf(l1 - m));
                float* o = out + ((size_t)(g0 + gg) * 2 + k) * 2;
                o[0] = l0 - lse;
                o[1] = l1 - lse;
            }
            __syncthreads();
        }
    }
}

extern "C" void kernel_launch(void* const* d_in, const int* in_sizes, int n_in,
                              void* d_out, int out_size, void* d_ws, size_t ws_size,
                              hipStream_t stream) {
    const float* x      = (const float*)d_in[0];
    const float* prompt = (const float*)d_in[1];
    const float* cls    = (const float*)d_in[2];
    const float* W1     = (const float*)d_in[3];
    const float* b1     = (const float*)d_in[4];
    const float* W2     = (const float*)d_in[5];
    const float* b2     = (const float*)d_in[6];
    const float* Wfc    = (const float*)d_in[7];
    const float* bfc    = (const float*)d_in[8];
    float* out = (float*)d_out;

    fused_kernel<<<NB, NT, 0, stream>>>(x, prompt, cls, W1, b1, W2, b2,
                                        Wfc, bfc, out);
}

// Round 7
// 145.761 us; speedup vs baseline: 1.0975x; 1.0575x over previous
//
#include <hip/hip_runtime.h>
#include <math.h>

namespace {
constexpr int IN_FEATS = 768;
constexpr int HIDDEN   = 128;
constexpr int G        = 1024;
constexpr int NPG      = 256;           // nodes per graph
constexpr int C4       = IN_FEATS / 4;  // 192 float4 columns per row
constexpr int NSTREAM  = 384;           // streamer threads (6 waves) — R4's layout
constexpr int NT       = 512;           // + 2 compute waves
constexpr int GPB      = 2;             // graphs per block
constexpr int NB       = G / GPB;       // 512 blocks -> 2 blocks/CU
typedef float f32x4 __attribute__((ext_vector_type(4)));
}

// Wave-specialized pipeline, one block per 2 graphs:
//   A(g0) by waves 0-5 (identical code to R4's proven stream loop)
//   A(g1) by waves 0-5  ||  B(g0): t0,hp,h0,h1 matvec by waves 6-7 (VALU/L2)
//   B(g1): t1-only matvec by waves 6-7 (short exposed tail)
//   relu / C / D as in R4.
// Closed form (verified R0-R6): deg(orig)=2, deg(prompt)=259, deg(class)=2;
//   ainv = 1/sqrt(518); r_g = relu(ainv*t_g + ainv*(h0+h1) + hp/259 + b1)
//   rc_k = relu(ainv*hp + 0.5*h_k + b1); v_gk = ainv*(r_g@W2) + 0.5*(rc_k@W2) + b2
//   out = log_softmax(v_gk @ Wfc + bfc)
__global__ __launch_bounds__(NT, 4) void fused_kernel(
    const float* __restrict__ x, const float* __restrict__ prompt,
    const float* __restrict__ cls,
    const float* __restrict__ W1, const float* __restrict__ bias1,
    const float* __restrict__ W2, const float* __restrict__ bias2,
    const float* __restrict__ Wfc, const float* __restrict__ bfc,
    float* __restrict__ out)
{
    __shared__ __align__(16) float S[GPB][IN_FEATS];   // 6 KB
    __shared__ f32x4  partA[2][C4];                    // 6 KB (reused g0 then g1)
    __shared__ float  cb[5][HIDDEN];                   // t0,t1,hp,h0,h1
    __shared__ __align__(16) float rbuf[4][HIDDEN];    // r0,r1,rc0,rc1
    __shared__ float  red[2][2];

    const int g0  = blockIdx.x * GPB;
    const int tid = threadIdx.x;
    const float ainv = 1.0f / sqrtf(518.0f);
    const bool streamer = tid < NSTREAM;

    const int p  = tid / C4;   // row parity 0/1 (streamers only)
    const int c4 = tid % C4;   // float4 column
    const f32x4* xb = reinterpret_cast<const f32x4*>(x);

    // ---- Phase A(g0): stream g0 (exact R4 loop) --------------------------
    if (streamer) {
        const f32x4* xp = xb + ((size_t)(g0 + 0) * NPG + p) * C4 + c4;
        f32x4 a0 = (f32x4)0.0f, a1 = a0, a2 = a0, a3 = a0;
        for (int i = 0; i < NPG / 2; i += 4) {
            const f32x4 v0 = __builtin_nontemporal_load(xp + (size_t)(2 * (i + 0)) * C4);
            const f32x4 v1 = __builtin_nontemporal_load(xp + (size_t)(2 * (i + 1)) * C4);
            const f32x4 v2 = __builtin_nontemporal_load(xp + (size_t)(2 * (i + 2)) * C4);
            const f32x4 v3 = __builtin_nontemporal_load(xp + (size_t)(2 * (i + 3)) * C4);
            a0 += v0; a1 += v1; a2 += v2; a3 += v3;
        }
        partA[p][c4] = (a0 + a1) + (a2 + a3);
    }
    __syncthreads();
    if (tid < C4) {
        const f32x4 q0 = partA[0][tid], q1 = partA[1][tid];
        *reinterpret_cast<f32x4*>(&S[0][tid * 4]) = q0 + q1;
    }
    __syncthreads();

    // ---- Phase A(g1) (streamers)  ||  B(g0) (computers) ------------------
    if (streamer) {
        const f32x4* xp = xb + ((size_t)(g0 + 1) * NPG + p) * C4 + c4;
        f32x4 a0 = (f32x4)0.0f, a1 = a0, a2 = a0, a3 = a0;
        for (int i = 0; i < NPG / 2; i += 4) {
            const f32x4 v0 = __builtin_nontemporal_load(xp + (size_t)(2 * (i + 0)) * C4);
            const f32x4 v1 = __builtin_nontemporal_load(xp + (size_t)(2 * (i + 1)) * C4);
            const f32x4 v2 = __builtin_nontemporal_load(xp + (size_t)(2 * (i + 2)) * C4);
            const f32x4 v3 = __builtin_nontemporal_load(xp + (size_t)(2 * (i + 3)) * C4);
            a0 += v0; a1 += v1; a2 += v2; a3 += v3;
        }
        partA[p][c4] = (a0 + a1) + (a2 + a3);
    } else {
        const int j = tid - NSTREAM;            // 0..127
        const float* w1p = W1 + j;
        float t0 = 0.f, hp = 0.f, h0 = 0.f, h1 = 0.f;
        for (int c = 0; c < IN_FEATS; c += 4) {
            const f32x4 s0 = *reinterpret_cast<const f32x4*>(&S[0][c]);  // LDS broadcast
            const f32x4 pv = *reinterpret_cast<const f32x4*>(prompt + c);       // uniform
            const f32x4 k0 = *reinterpret_cast<const f32x4*>(cls + c);          // uniform
            const f32x4 k1 = *reinterpret_cast<const f32x4*>(cls + IN_FEATS + c);
            const float w0 = w1p[(size_t)(c + 0) * HIDDEN];  // coalesced L2
            const float w1 = w1p[(size_t)(c + 1) * HIDDEN];
            const float w2 = w1p[(size_t)(c + 2) * HIDDEN];
            const float w3 = w1p[(size_t)(c + 3) * HIDDEN];
            t0 = fmaf(s0.x, w0, t0); hp = fmaf(pv.x, w0, hp);
            h0 = fmaf(k0.x, w0, h0); h1 = fmaf(k1.x, w0, h1);
            t0 = fmaf(s0.y, w1, t0); hp = fmaf(pv.y, w1, hp);
            h0 = fmaf(k0.y, w1, h0); h1 = fmaf(k1.y, w1, h1);
            t0 = fmaf(s0.z, w2, t0); hp = fmaf(pv.z, w2, hp);
            h0 = fmaf(k0.z, w2, h0); h1 = fmaf(k1.z, w2, h1);
            t0 = fmaf(s0.w, w3, t0); hp = fmaf(pv.w, w3, hp);
            h0 = fmaf(k0.w, w3, h0); h1 = fmaf(k1.w, w3, h1);
        }
        cb[0][j] = t0; cb[2][j] = hp; cb[3][j] = h0; cb[4][j] = h1;
    }
    __syncthreads();
    if (tid < C4) {
        const f32x4 q0 = partA[0][tid], q1 = partA[1][tid];
        *reinterpret_cast<f32x4*>(&S[1][tid * 4]) = q0 + q1;
    }
    __syncthreads();

    // ---- Phase B(g1): t1-only matvec (computers; short exposed tail) -----
    if (!streamer) {
        const int j = tid - NSTREAM;
        const float* w1p = W1 + j;
        float t1 = 0.f;
        for (int c = 0; c < IN_FEATS; c += 4) {
            const f32x4 s1 = *reinterpret_cast<const f32x4*>(&S[1][c]);
            const float w0 = w1p[(size_t)(c + 0) * HIDDEN];
            const float w1 = w1p[(size_t)(c + 1) * HIDDEN];
            const float w2 = w1p[(size_t)(c + 2) * HIDDEN];
            const float w3 = w1p[(size_t)(c + 3) * HIDDEN];
            t1 = fmaf(s1.x, w0, t1);
            t1 = fmaf(s1.y, w1, t1);
            t1 = fmaf(s1.z, w2, t1);
            t1 = fmaf(s1.w, w3, t1);
        }
        cb[1][j] = t1;
    }
    __syncthreads();

    // ---- relu combine ----------------------------------------------------
    if (tid < HIDDEN) {
        const float t0 = cb[0][tid], t1 = cb[1][tid];
        const float hp = cb[2][tid], h0 = cb[3][tid], h1 = cb[4][tid];
        const float b  = bias1[tid];
        const float C1 = ainv * (h0 + h1) + hp * (1.0f / 259.0f) + b;
        rbuf[0][tid] = fmaxf(fmaf(ainv, t0, C1), 0.f);                  // r_g0
        rbuf[1][tid] = fmaxf(fmaf(ainv, t1, C1), 0.f);                  // r_g1
        rbuf[2][tid] = fmaxf(fmaf(ainv, hp, fmaf(0.5f, h0, b)), 0.f);   // rc0
        rbuf[3][tid] = fmaxf(fmaf(ainv, hp, fmaf(0.5f, h1, b)), 0.f);   // rc1
    }
    __syncthreads();

    // ---- Phase C: four 128->128 matvecs sharing each W2 load -------------
    float u0 = 0.f, u1 = 0.f, uc0 = 0.f, uc1 = 0.f;
    if (tid < HIDDEN) {
        const float* w2p = W2 + tid;
        for (int c = 0; c < HIDDEN; c += 4) {
            const f32x4 r0 = *reinterpret_cast<const f32x4*>(&rbuf[0][c]);
            const f32x4 r1 = *reinterpret_cast<const f32x4*>(&rbuf[1][c]);
            const f32x4 q0 = *reinterpret_cast<const f32x4*>(&rbuf[2][c]);
            const f32x4 q1 = *reinterpret_cast<const f32x4*>(&rbuf[3][c]);
            const float wa = w2p[(size_t)(c + 0) * HIDDEN];
            const float wb = w2p[(size_t)(c + 1) * HIDDEN];
            const float wc = w2p[(size_t)(c + 2) * HIDDEN];
            const float wd = w2p[(size_t)(c + 3) * HIDDEN];
            u0  = fmaf(r0.x, wa, u0);  u1  = fmaf(r1.x, wa, u1);
            uc0 = fmaf(q0.x, wa, uc0); uc1 = fmaf(q1.x, wa, uc1);
            u0  = fmaf(r0.y, wb, u0);  u1  = fmaf(r1.y, wb, u1);
            uc0 = fmaf(q0.y, wb, uc0); uc1 = fmaf(q1.y, wb, uc1);
            u0  = fmaf(r0.z, wc, u0);  u1  = fmaf(r1.z, wc, u1);
            uc0 = fmaf(q0.z, wc, uc0); uc1 = fmaf(q1.z, wc, uc1);
            u0  = fmaf(r0.w, wd, u0);  u1  = fmaf(r1.w, wd, u1);
            uc0 = fmaf(q0.w, wd, uc0); uc1 = fmaf(q1.w, wd, uc1);
        }
    }

    // ---- Phase D: logits + log_softmax per (graph, class) ----------------
    const float bfc0 = bfc[0], bfc1 = bfc[1];
    for (int gg = 0; gg < GPB; ++gg) {
        for (int k = 0; k < 2; ++k) {
            float p0 = 0.f, p1 = 0.f;
            if (tid < HIDDEN) {
                const float ug = (gg == 0) ? u0 : u1;
                const float uk = (k == 0) ? uc0 : uc1;
                const float v  = fmaf(ainv, ug, fmaf(0.5f, uk, bias2[tid]));
                p0 = v * Wfc[tid * 2 + 0];
                p1 = v * Wfc[tid * 2 + 1];
                #pragma unroll
                for (int off = 32; off > 0; off >>= 1) {
                    p0 += __shfl_down(p0, off);
                    p1 += __shfl_down(p1, off);
                }
                if ((tid & 63) == 0) { red[tid >> 6][0] = p0; red[tid >> 6][1] = p1; }
            }
            __syncthreads();
            if (tid == 0) {
                const float l0 = red[0][0] + red[1][0] + bfc0;
                const float l1 = red[0][1] + red[1][1] + bfc1;
                const float m   = fmaxf(l0, l1);
                const float lse = m + logf(expf(l0 - m) + expf(l1 - m));
                float* o = out + ((size_t)(g0 + gg) * 2 + k) * 2;
                o[0] = l0 - lse;
                o[1] = l1 - lse;
            }
            __syncthreads();
        }
    }
}

extern "C" void kernel_launch(void* const* d_in, const int* in_sizes, int n_in,
                              void* d_out, int out_size, void* d_ws, size_t ws_size,
                              hipStream_t stream) {
    const float* x      = (const float*)d_in[0];
    const float* prompt = (const float*)d_in[1];
    const float* cls    = (const float*)d_in[2];
    const float* W1     = (const float*)d_in[3];
    const float* b1     = (const float*)d_in[4];
    const float* W2     = (const float*)d_in[5];
    const float* b2     = (const float*)d_in[6];
    const float* Wfc    = (const float*)d_in[7];
    const float* bfc    = (const float*)d_in[8];
    float* out = (float*)d_out;

    fused_kernel<<<NB, NT, 0, stream>>>(x, prompt, cls, W1, b1, W2, b2,
                                        Wfc, bfc, out);
}